// Round 4
// baseline (163.252 us; speedup 1.0000x reference)
//
#include <hip/hip_runtime.h>

// WeightedDiceLoss on MI355X -- round 11: hrow-ring (horizontal-first
// separable box). R10 post-mortem: all pipes ~20% busy, time latency-bound on
// the per-step serial chain (3 LDS reads -> unpack -> 8-deep prefix -> 17
// dependent ds_bpermute -> weight). Fix: flip the separable order. At preload,
// compute each target row's horizontal 31-box sum (hrow) ONCE -- 62
// independent rows/block, perfect ILP, off the critical path -- and store
// fp16 hrow in LDS. Hot loop per output row is then just
//   box += hrow[h+15] - hrow[h-16]   (2 LDS b128 reads, 16 cvt, 16 add)
// plus the weight/accumulate math (~60 VALU): NO shuffles, NO prefix chain,
// NO raw-target ring. Center target row re-read from global (streamed
// moments earlier -> L2/L3 hit; R10 proved L3 carries the set: FETCH 67MB).
// fp16 hrow (<=31, err ~0.016) keeps avg error ~5e-5 -- inside tolerance.
// Ring is read-only after one barrier; hot loop barrier-free (R10 skeleton).
//
// input, target: (64,1,512,512) fp32. Output: scalar fp32.
// weight = 1 + 5*|box31(target) - target|; loss = 1 - (2*I+1)/(A+B+1).

#define BATCH 64
#define H     512
#define W     512
#define RBAND 32                      // rows per block (4 waves x 8 rows)
#define SLOTS 62                      // hrow rows R0-15 .. R0+46
#define NBLK  (BATCH * (H / RBAND))   // 1024 blocks

typedef _Float16 half8 __attribute__((ext_vector_type(8)));

__global__ __launch_bounds__(256, 2) void fused_kernel(const float* __restrict__ tgt,
                                                       const float* __restrict__ inp,
                                                       float4* __restrict__ partials) {
    const int tid  = threadIdx.x;
    const int lane = tid & 63;
    const int wv   = tid >> 6;
    // XCD-contiguous work id (bijective, 1024 % 8 == 0): adjacent bands of the
    // same image land on the same XCD -> halo/center re-reads hit XCD L2.
    const int g    = blockIdx.x;
    const int blk  = ((g & 7) << 7) | (g >> 3);
    const int band = blk & 15;                    // H/RBAND = 16 bands
    const int b    = blk >> 4;
    const int R0   = band * RBAND;
    const float* timg = tgt + (size_t)b * H * W;
    const float* iimg = inp + (size_t)b * H * W;

    // slot(row) = row - R0 + 15, rows R0-15 .. R0+46 -> slots 0..61.
    __shared__ __align__(16) unsigned ring[SLOTS * 256];   // 63488 B -> 2 blocks/CU

    const int col0 = lane * 8;               // this lane's 8 columns
    const int ofs  = lane * 4;               // lane's uint4/half8 dword offset

    // wave-edge masks for the horizontal window (zero column padding)
    const float mL1 = (lane >= 1) ? 1.f : 0.f;
    const float mR1 = (lane <= 62) ? 1.f : 0.f;
    const float mL2 = (lane >= 2) ? 1.f : 0.f;
    const float mR2 = (lane <= 61) ? 1.f : 0.f;

    // ---- preload: build hrow for 62 rows cooperatively --------------------
    // Each row: load raw fp32 row, horizontal 31-window (verified
    // segment-sum + shuffles), convert fp16, one b128 LDS write.
    // Out-of-image rows written as ZEROS -> hot loop guard-free.
    #pragma unroll 2
    for (int k = 0; k < 16; ++k) {
        const int idx = 4 * k + wv;          // slot, 0..63 (guarded < 62)
        if (idx < SLOTS) {
            const int row = R0 - 15 + idx;
            float t[8];
            #pragma unroll
            for (int q = 0; q < 8; ++q) t[q] = 0.f;
            if (row >= 0 && row < H) {
                const float4 v0 = *(const float4*)(timg + (size_t)row * W + col0);
                const float4 v1 = *(const float4*)(timg + (size_t)row * W + col0 + 4);
                t[0] = v0.x; t[1] = v0.y; t[2] = v0.z; t[3] = v0.w;
                t[4] = v1.x; t[5] = v1.y; t[6] = v1.z; t[7] = v1.w;
            }
            // horizontal 31-window over this row (zero padding at col edges)
            const float p1 = t[0];
            const float p2 = p1 + t[1];
            const float p3 = p2 + t[2];
            const float p4 = p3 + t[3];
            const float p5 = p4 + t[4];
            const float p6 = p5 + t[5];
            const float p7 = p6 + t[6];
            const float s  = p7 + t[7];
            const float f1 = s - p1, f2 = s - p2, f3 = s - p3, f4 = s - p4;
            const float f5 = s - p5, f6 = s - p6, f7 = s - p7;

            const float sL1 = __shfl_up(s, 1, 64);
            const float sR1 = __shfl_down(s, 1, 64);
            const float g1 = __shfl_up(f1, 2, 64);
            const float g2 = __shfl_up(f2, 2, 64);
            const float g3 = __shfl_up(f3, 2, 64);
            const float g4 = __shfl_up(f4, 2, 64);
            const float g5 = __shfl_up(f5, 2, 64);
            const float g6 = __shfl_up(f6, 2, 64);
            const float g7 = __shfl_up(f7, 2, 64);
            const float q1 = __shfl_down(p1, 2, 64);
            const float q2 = __shfl_down(p2, 2, 64);
            const float q3 = __shfl_down(p3, 2, 64);
            const float q4 = __shfl_down(p4, 2, 64);
            const float q5 = __shfl_down(p5, 2, 64);
            const float q6 = __shfl_down(p6, 2, 64);
            const float q7 = __shfl_down(p7, 2, 64);

            const float S3 = fmaf(mL1, sL1, fmaf(mR1, sR1, s));
            half8 hv;
            hv[0] = (_Float16)fmaf(mL2, g1, S3);
            hv[1] = (_Float16)fmaf(mL2, g2, fmaf(mR2, q1, S3));
            hv[2] = (_Float16)fmaf(mL2, g3, fmaf(mR2, q2, S3));
            hv[3] = (_Float16)fmaf(mL2, g4, fmaf(mR2, q3, S3));
            hv[4] = (_Float16)fmaf(mL2, g5, fmaf(mR2, q4, S3));
            hv[5] = (_Float16)fmaf(mL2, g6, fmaf(mR2, q5, S3));
            hv[6] = (_Float16)fmaf(mL2, g7, fmaf(mR2, q6, S3));
            hv[7] = (_Float16)fmaf(mR2, q7, S3);
            *(half8*)&ring[idx * 256 + ofs] = hv;
        }
    }
    __syncthreads();
    // Ring is READ-ONLY from here until the final reduction.

    // ---- init 2D box for first output row h0 = R0+8*wv --------------------
    // box = sum of hrow rows h0-15..h0+15 = slots 8wv .. 8wv+30.
    const int base = 8 * wv;
    float box[8];
    #pragma unroll
    for (int q = 0; q < 8; ++q) box[q] = 0.f;
    #pragma unroll 4
    for (int jj = 0; jj < 31; ++jj) {
        const half8 c = *(const half8*)&ring[(base + jj) * 256 + ofs];
        #pragma unroll
        for (int q = 0; q < 8; ++q) box[q] += (float)c[q];
    }

    const float inv = 1.0f / 961.0f;
    float aI = 0.f, aA = 0.f, aB = 0.f;

    #pragma unroll
    for (int st = 0; st < 8; ++st) {
        const int h = R0 + base + st;        // this step's output row (< H)

        // ---- slide 2D box: += hrow[h+15] - hrow[h-16] (slots in-bounds,
        //      out-of-image rows are zero slots -> no guards) --------------
        if (st > 0) {
            const half8 a = *(const half8*)&ring[(base + st + 30) * 256 + ofs];
            const half8 s = *(const half8*)&ring[(base + st - 1) * 256 + ofs];
            #pragma unroll
            for (int q = 0; q < 8; ++q) box[q] += (float)a[q] - (float)s[q];
        }

        // ---- per-pixel weight + accumulate (center row from global:
        //      streamed during preload -> L2/L3 hit) -----------------------
        const float4 i0 = *(const float4*)(iimg + (size_t)h * W + col0);
        const float4 i1 = *(const float4*)(iimg + (size_t)h * W + col0 + 4);
        const float4 t0 = *(const float4*)(timg + (size_t)h * W + col0);
        const float4 t1 = *(const float4*)(timg + (size_t)h * W + col0 + 4);
        const float tv[8] = {t0.x, t0.y, t0.z, t0.w, t1.x, t1.y, t1.z, t1.w};
        const float iv[8] = {i0.x, i0.y, i0.z, i0.w, i1.x, i1.y, i1.z, i1.w};

        #pragma unroll
        for (int k = 0; k < 8; ++k) {
            const float wgt = fmaf(5.0f, fabsf(fmaf(box[k], inv, -tv[k])), 1.0f);
            const float tw  = tv[k] * wgt;
            aI = fmaf(iv[k], tw, aI);
            aA = fmaf(iv[k], wgt, aA);
            aB += tw;
        }
    }

    // ---- wave reduction (64 lanes) ----------------------------------------
    #pragma unroll
    for (int off = 32; off > 0; off >>= 1) {
        aI += __shfl_down(aI, off, 64);
        aA += __shfl_down(aA, off, 64);
        aB += __shfl_down(aB, off, 64);
    }
    // All ring READS must finish before storage reuse (waves free-run).
    __syncthreads();
    float* rf = (float*)ring;
    if (lane == 0) { rf[wv] = aI; rf[8 + wv] = aA; rf[16 + wv] = aB; }
    __syncthreads();
    if (tid == 0) {
        float4 o;
        o.x = rf[0] + rf[1] + rf[2] + rf[3];
        o.y = rf[8] + rf[9] + rf[10] + rf[11];
        o.z = rf[16] + rf[17] + rf[18] + rf[19];
        o.w = 0.f;
        partials[g] = o;
    }
}

// ---------------------------------------------------------------------------
// Reduce NBLK (1024) partials + finalize. One block, 1024 threads (16 waves).
// ---------------------------------------------------------------------------
__global__ __launch_bounds__(1024) void reduce_kernel(const float4* __restrict__ partials,
                                                      float* __restrict__ out) {
    const int tid = threadIdx.x;
    const float4 v = partials[tid];          // exactly 1024 entries
    float aI = v.x, aA = v.y, aB = v.z;
    #pragma unroll
    for (int off = 32; off > 0; off >>= 1) {
        aI += __shfl_down(aI, off, 64);
        aA += __shfl_down(aA, off, 64);
        aB += __shfl_down(aB, off, 64);
    }
    __shared__ float s[3][16];
    const int wvx = tid >> 6, ln = tid & 63;
    if (ln == 0) { s[0][wvx] = aI; s[1][wvx] = aA; s[2][wvx] = aB; }
    __syncthreads();
    if (tid == 0) {
        float I = 0.f, A = 0.f, Bv = 0.f;
        #pragma unroll
        for (int k = 0; k < 16; ++k) { I += s[0][k]; A += s[1][k]; Bv += s[2][k]; }
        out[0] = 1.0f - (2.0f * I + 1.0f) / (A + Bv + 1.0f);
    }
}

extern "C" void kernel_launch(void* const* d_in, const int* in_sizes, int n_in,
                              void* d_out, int out_size, void* d_ws, size_t ws_size,
                              hipStream_t stream) {
    const float* inp = (const float*)d_in[0];   // "input"
    const float* tgt = (const float*)d_in[1];   // "target"
    float* out = (float*)d_out;

    // workspace: [0, NBLK*16) per-block partials (float4); written before read.
    float4* partials = (float4*)d_ws;

    fused_kernel<<<NBLK, 256, 0, stream>>>(tgt, inp, partials);
    reduce_kernel<<<1, 1024, 0, stream>>>(partials, out);
}